// Round 1
// baseline (1403.636 us; speedup 1.0000x reference)
//
#include <hip/hip_runtime.h>

// Problem constants (match reference setup_inputs)
#define N_EDGES 1250000
#define N_NODES 50000
#define D_FEAT 64

// 16 threads per edge; each thread owns 4 consecutive floats (float4).
// Wave of 64 lanes covers 4 edges; edge_attr access is a fully coalesced
// 1 KiB per wave. x-row gathers are 256 B contiguous per 16-lane group
// (L2-resident: x is 12.8 MB < 32 MB aggregate L2).
__global__ __launch_bounds__(256) void msg_scatter_kernel(
    const float* __restrict__ x,
    const float* __restrict__ ea,
    const int* __restrict__ src_idx,
    const int* __restrict__ dst_idx,
    float* __restrict__ out)
{
    const long long total = (long long)N_EDGES * 16;
    const long long stride = (long long)gridDim.x * blockDim.x;
    for (long long i = (long long)blockIdx.x * blockDim.x + threadIdx.x;
         i < total; i += stride) {
        const int e    = (int)(i >> 4);
        const int part = (int)(i & 15);

        const int s = src_idx[e];
        const int d = dst_idx[e];

        const float4 a  = *reinterpret_cast<const float4*>(ea + (size_t)e * D_FEAT + part * 4);
        const float4 xs = *reinterpret_cast<const float4*>(x  + (size_t)s * D_FEAT + part * 4);
        const float4 xd = *reinterpret_cast<const float4*>(x  + (size_t)d * D_FEAT + part * 4);

        float* o = out + (size_t)d * D_FEAT + part * 4;
        atomicAdd(o + 0, a.x + xs.x + xd.x);
        atomicAdd(o + 1, a.y + xs.y + xd.y);
        atomicAdd(o + 2, a.z + xs.z + xd.z);
        atomicAdd(o + 3, a.w + xs.w + xd.w);
    }
}

extern "C" void kernel_launch(void* const* d_in, const int* in_sizes, int n_in,
                              void* d_out, int out_size, void* d_ws, size_t ws_size,
                              hipStream_t stream) {
    const float* x   = (const float*)d_in[0];
    const float* ea  = (const float*)d_in[1];
    const int*   idx = (const int*)d_in[2];   // [2, E]: row 0 = src, row 1 = dst

    float* out = (float*)d_out;

    // d_out is re-poisoned to 0xAA before every timed call — zero it.
    hipMemsetAsync(out, 0, (size_t)out_size * sizeof(float), stream);

    const int block = 256;
    const int grid  = 2048;  // grid-stride; ~8 blocks/CU worth of waves
    msg_scatter_kernel<<<grid, block, 0, stream>>>(x, ea, idx, idx + N_EDGES, out);
}

// Round 2
// 704.266 us; speedup vs baseline: 1.9930x; 1.9930x over previous
//
#include <hip/hip_runtime.h>

#define N_EDGES 1250000
#define N_NODES 50000
#define D_FEAT 64

// ---------------------------------------------------------------------------
// Phase 1: histogram of destination degrees.  int atomics on a 200 KB array
// (L2-resident) — cheap compared to 80M f32 atomics on the 12.8 MB output.
// ---------------------------------------------------------------------------
__global__ __launch_bounds__(256) void hist_kernel(
    const int* __restrict__ dst, int* __restrict__ deg)
{
    int e = blockIdx.x * blockDim.x + threadIdx.x;
    if (e < N_EDGES) atomicAdd(&deg[dst[e]], 1);
}

// ---------------------------------------------------------------------------
// Phase 2: exclusive scan of deg -> offs[0..N], and copy offs into cursor
// (reusing the deg array) for the fill phase.  Single 1024-thread block,
// Hillis-Steele over 1024-element chunks.
// ---------------------------------------------------------------------------
__global__ __launch_bounds__(1024) void scan_kernel(
    int* __restrict__ deg /* in: counts, out: cursor=offs */,
    int* __restrict__ offs)
{
    __shared__ int lds[1024];
    __shared__ int carry_s;
    if (threadIdx.x == 0) carry_s = 0;
    __syncthreads();

    for (int base = 0; base < N_NODES; base += 1024) {
        int i = base + (int)threadIdx.x;
        int v = (i < N_NODES) ? deg[i] : 0;
        lds[threadIdx.x] = v;
        __syncthreads();
        for (int off = 1; off < 1024; off <<= 1) {
            int t = (threadIdx.x >= (unsigned)off) ? lds[threadIdx.x - off] : 0;
            __syncthreads();
            lds[threadIdx.x] += t;
            __syncthreads();
        }
        int incl = lds[threadIdx.x];
        int c = carry_s;
        if (i < N_NODES) {
            int excl = c + incl - v;
            offs[i] = excl;
            deg[i]  = excl;   // cursor for fill phase
        }
        __syncthreads();
        if (threadIdx.x == 1023) carry_s = c + lds[1023];
        __syncthreads();
    }
    if (threadIdx.x == 0) offs[N_NODES] = carry_s;  // == N_EDGES
}

// ---------------------------------------------------------------------------
// Phase 3: scatter edge ids into CSR buckets.
// ---------------------------------------------------------------------------
__global__ __launch_bounds__(256) void fill_kernel(
    const int* __restrict__ dst, int* __restrict__ cursor,
    int* __restrict__ elist)
{
    int e = blockIdx.x * blockDim.x + threadIdx.x;
    if (e < N_EDGES) {
        int pos = atomicAdd(&cursor[dst[e]], 1);
        elist[pos] = e;
    }
}

// ---------------------------------------------------------------------------
// Phase 4: gather.  16 lanes per node, each lane owns one float4 (4 feats).
// out[d] = sum_e x[src_e] + deg(d)*x[d] + sum_e edge_attr[e]; single
// non-atomic write per output element.
// ---------------------------------------------------------------------------
__global__ __launch_bounds__(256) void gather_kernel(
    const float* __restrict__ x,
    const float* __restrict__ ea,
    const int* __restrict__ src,
    const int* __restrict__ offs,
    const int* __restrict__ elist,
    float* __restrict__ out)
{
    int gt = blockIdx.x * blockDim.x + threadIdx.x;   // 50000*16 threads
    int n    = gt >> 4;
    int part = gt & 15;
    if (n >= N_NODES) return;

    int beg = offs[n];
    int end = offs[n + 1];

    float4 acc = make_float4(0.f, 0.f, 0.f, 0.f);

    int j = beg;
    // unroll by 2 for memory-level parallelism
    for (; j + 1 < end; j += 2) {
        int e0 = elist[j];
        int e1 = elist[j + 1];
        int s0 = src[e0];
        int s1 = src[e1];
        float4 a0  = *reinterpret_cast<const float4*>(ea + (size_t)e0 * D_FEAT + part * 4);
        float4 xs0 = *reinterpret_cast<const float4*>(x  + (size_t)s0 * D_FEAT + part * 4);
        float4 a1  = *reinterpret_cast<const float4*>(ea + (size_t)e1 * D_FEAT + part * 4);
        float4 xs1 = *reinterpret_cast<const float4*>(x  + (size_t)s1 * D_FEAT + part * 4);
        acc.x += a0.x + xs0.x + a1.x + xs1.x;
        acc.y += a0.y + xs0.y + a1.y + xs1.y;
        acc.z += a0.z + xs0.z + a1.z + xs1.z;
        acc.w += a0.w + xs0.w + a1.w + xs1.w;
    }
    if (j < end) {
        int e0 = elist[j];
        int s0 = src[e0];
        float4 a0  = *reinterpret_cast<const float4*>(ea + (size_t)e0 * D_FEAT + part * 4);
        float4 xs0 = *reinterpret_cast<const float4*>(x  + (size_t)s0 * D_FEAT + part * 4);
        acc.x += a0.x + xs0.x;
        acc.y += a0.y + xs0.y;
        acc.z += a0.z + xs0.z;
        acc.w += a0.w + xs0.w;
    }

    // + deg * x[n]
    float degf = (float)(end - beg);
    float4 xd = *reinterpret_cast<const float4*>(x + (size_t)n * D_FEAT + part * 4);
    acc.x += degf * xd.x;
    acc.y += degf * xd.y;
    acc.z += degf * xd.z;
    acc.w += degf * xd.w;

    *reinterpret_cast<float4*>(out + (size_t)n * D_FEAT + part * 4) = acc;
}

extern "C" void kernel_launch(void* const* d_in, const int* in_sizes, int n_in,
                              void* d_out, int out_size, void* d_ws, size_t ws_size,
                              hipStream_t stream) {
    const float* x   = (const float*)d_in[0];
    const float* ea  = (const float*)d_in[1];
    const int*   idx = (const int*)d_in[2];   // [2, E]: row 0 = src, row 1 = dst
    const int* src = idx;
    const int* dst = idx + N_EDGES;

    float* out = (float*)d_out;

    // workspace layout (ints): deg/cursor[N], offs[N+1], elist[E]  (~5.2 MB)
    int* deg   = (int*)d_ws;
    int* offs  = deg + N_NODES;
    int* elist = offs + N_NODES + 1;

    hipMemsetAsync(deg, 0, (size_t)N_NODES * sizeof(int), stream);

    const int block = 256;
    const int gridE = (N_EDGES + block - 1) / block;

    hist_kernel<<<gridE, block, 0, stream>>>(dst, deg);
    scan_kernel<<<1, 1024, 0, stream>>>(deg, offs);
    fill_kernel<<<gridE, block, 0, stream>>>(dst, deg, elist);

    const int gridN = (N_NODES * 16 + block - 1) / block;  // 3125
    gather_kernel<<<gridN, block, 0, stream>>>(x, ea, src, offs, elist, out);
}

// Round 3
// 551.503 us; speedup vs baseline: 2.5451x; 1.2770x over previous
//
#include <hip/hip_runtime.h>

#define N_EDGES 1250000
#define N_NODES 50000
#define D_FEAT 64
#define CAP 64   // fixed bucket capacity; expected deg=25, realized max ~50.
                 // Overflow (any input) handled exactly via overflow list.

// ---------------------------------------------------------------------------
// Phase 1: ticketed bucket fill.  pos = cnt[dst]++ ; elist[dst*CAP+pos] = e.
// No histogram, no scan.  1.25M int atomics on a 200 KB L2-resident array.
// Edges whose ticket >= CAP go to a global overflow list (≈never for this
// distribution, but keeps the kernel exact for arbitrary inputs).
// ---------------------------------------------------------------------------
__global__ __launch_bounds__(256) void fill_kernel(
    const int* __restrict__ dst,
    int* __restrict__ cnt,          // [N_NODES] zeroed
    int* __restrict__ ovc,          // [1] zeroed
    int* __restrict__ elist,        // [N_NODES*CAP]
    int* __restrict__ ov)           // [N_EDGES] overflow edge ids
{
    int i = blockIdx.x * blockDim.x + threadIdx.x;   // E/4 threads
    if (i >= N_EDGES / 4) return;
    int4 d4 = reinterpret_cast<const int4*>(dst)[i];
    int e0 = i * 4;
    #pragma unroll
    for (int k = 0; k < 4; ++k) {
        int d = (k == 0) ? d4.x : (k == 1) ? d4.y : (k == 2) ? d4.z : d4.w;
        int t = atomicAdd(&cnt[d], 1);
        if (t < CAP) {
            elist[(size_t)d * CAP + t] = e0 + k;
        } else {
            int p = atomicAdd(ovc, 1);
            ov[p] = e0 + k;
        }
    }
}

// ---------------------------------------------------------------------------
// Phase 2: gather.  16 lanes per node, each lane owns one float4 (4 feats).
// out[n] = sum_e (x[src_e] + ea[e]) + deg*x[n]; one non-atomic write/row.
// Rows with deg=0 write zeros (d_out is poisoned, so this is required).
// ---------------------------------------------------------------------------
__global__ __launch_bounds__(256) void gather_kernel(
    const float* __restrict__ x,
    const float* __restrict__ ea,
    const int* __restrict__ src,
    const int* __restrict__ cnt,
    const int* __restrict__ elist,
    float* __restrict__ out)
{
    int gt = blockIdx.x * blockDim.x + threadIdx.x;   // N_NODES*16 threads
    int n    = gt >> 4;
    int part = gt & 15;
    if (n >= N_NODES) return;

    int deg = cnt[n];
    if (deg > CAP) deg = CAP;        // overflow edges handled separately
    const int* bucket = elist + (size_t)n * CAP;

    float4 acc = make_float4(0.f, 0.f, 0.f, 0.f);

    int j = 0;
    for (; j + 3 < deg; j += 4) {
        int e0 = bucket[j + 0], e1 = bucket[j + 1];
        int e2 = bucket[j + 2], e3 = bucket[j + 3];
        int s0 = src[e0], s1 = src[e1], s2 = src[e2], s3 = src[e3];
        float4 a0  = *reinterpret_cast<const float4*>(ea + (size_t)e0 * D_FEAT + part * 4);
        float4 a1  = *reinterpret_cast<const float4*>(ea + (size_t)e1 * D_FEAT + part * 4);
        float4 a2  = *reinterpret_cast<const float4*>(ea + (size_t)e2 * D_FEAT + part * 4);
        float4 a3  = *reinterpret_cast<const float4*>(ea + (size_t)e3 * D_FEAT + part * 4);
        float4 x0  = *reinterpret_cast<const float4*>(x  + (size_t)s0 * D_FEAT + part * 4);
        float4 x1  = *reinterpret_cast<const float4*>(x  + (size_t)s1 * D_FEAT + part * 4);
        float4 x2  = *reinterpret_cast<const float4*>(x  + (size_t)s2 * D_FEAT + part * 4);
        float4 x3  = *reinterpret_cast<const float4*>(x  + (size_t)s3 * D_FEAT + part * 4);
        acc.x += (a0.x + x0.x) + (a1.x + x1.x) + (a2.x + x2.x) + (a3.x + x3.x);
        acc.y += (a0.y + x0.y) + (a1.y + x1.y) + (a2.y + x2.y) + (a3.y + x3.y);
        acc.z += (a0.z + x0.z) + (a1.z + x1.z) + (a2.z + x2.z) + (a3.z + x3.z);
        acc.w += (a0.w + x0.w) + (a1.w + x1.w) + (a2.w + x2.w) + (a3.w + x3.w);
    }
    for (; j < deg; ++j) {
        int e0 = bucket[j];
        int s0 = src[e0];
        float4 a0 = *reinterpret_cast<const float4*>(ea + (size_t)e0 * D_FEAT + part * 4);
        float4 x0 = *reinterpret_cast<const float4*>(x  + (size_t)s0 * D_FEAT + part * 4);
        acc.x += a0.x + x0.x;
        acc.y += a0.y + x0.y;
        acc.z += a0.z + x0.z;
        acc.w += a0.w + x0.w;
    }

    float degf = (float)deg;
    float4 xd = *reinterpret_cast<const float4*>(x + (size_t)n * D_FEAT + part * 4);
    acc.x += degf * xd.x;
    acc.y += degf * xd.y;
    acc.z += degf * xd.z;
    acc.w += degf * xd.w;

    *reinterpret_cast<float4*>(out + (size_t)n * D_FEAT + part * 4) = acc;
}

// ---------------------------------------------------------------------------
// Phase 3: overflow scatter (exactness fallback; ~0 work for random input).
// Runs after gather so it can atomically add onto the written rows.
// ---------------------------------------------------------------------------
__global__ __launch_bounds__(256) void overflow_kernel(
    const float* __restrict__ x,
    const float* __restrict__ ea,
    const int* __restrict__ src,
    const int* __restrict__ dst,
    const int* __restrict__ ov,
    const int* __restrict__ ovc,
    float* __restrict__ out)
{
    int total = (*ovc) * 16;
    int stride = gridDim.x * blockDim.x;
    for (int i = blockIdx.x * blockDim.x + threadIdx.x; i < total; i += stride) {
        int o    = i >> 4;
        int part = i & 15;
        int e = ov[o];
        int s = src[e];
        int d = dst[e];
        float4 a  = *reinterpret_cast<const float4*>(ea + (size_t)e * D_FEAT + part * 4);
        float4 xs = *reinterpret_cast<const float4*>(x  + (size_t)s * D_FEAT + part * 4);
        float4 xd = *reinterpret_cast<const float4*>(x  + (size_t)d * D_FEAT + part * 4);
        float* o_ = out + (size_t)d * D_FEAT + part * 4;
        atomicAdd(o_ + 0, a.x + xs.x + xd.x);
        atomicAdd(o_ + 1, a.y + xs.y + xd.y);
        atomicAdd(o_ + 2, a.z + xs.z + xd.z);
        atomicAdd(o_ + 3, a.w + xs.w + xd.w);
    }
}

extern "C" void kernel_launch(void* const* d_in, const int* in_sizes, int n_in,
                              void* d_out, int out_size, void* d_ws, size_t ws_size,
                              hipStream_t stream) {
    const float* x   = (const float*)d_in[0];
    const float* ea  = (const float*)d_in[1];
    const int*   idx = (const int*)d_in[2];   // [2, E]: row 0 = src, row 1 = dst
    const int* src = idx;
    const int* dst = idx + N_EDGES;

    float* out = (float*)d_out;

    // workspace (ints): cnt[N], ovc[1]+pad, elist[N*CAP], ov[E]  (~18.3 MB)
    int* cnt   = (int*)d_ws;
    int* ovc   = cnt + N_NODES;
    int* elist = cnt + N_NODES + 16;
    int* ov    = elist + (size_t)N_NODES * CAP;

    // zero cnt + ovc in one memset (elist/ov need no init)
    hipMemsetAsync(cnt, 0, (size_t)(N_NODES + 16) * sizeof(int), stream);

    const int block = 256;
    const int gridF = (N_EDGES / 4 + block - 1) / block;     // 1221
    fill_kernel<<<gridF, block, 0, stream>>>(dst, cnt, ovc, elist, ov);

    const int gridN = (N_NODES * 16 + block - 1) / block;    // 3125
    gather_kernel<<<gridN, block, 0, stream>>>(x, ea, src, cnt, elist, out);

    overflow_kernel<<<64, block, 0, stream>>>(x, ea, src, dst, ov, ovc, out);
}